// Round 17
// baseline (442.534 us; speedup 1.0000x reference)
//
#include <hip/hip_runtime.h>
#include <hip/hip_bf16.h>

typedef _Float16 half8 __attribute__((ext_vector_type(8)));
typedef _Float16 half4v __attribute__((ext_vector_type(4)));
typedef float floatx4 __attribute__((ext_vector_type(4)));
typedef float floatx16 __attribute__((ext_vector_type(16)));

// ---------------------------------------------------------------------------
// R17: 32-row tiles, chunk-major layout, PING-PONG act buffers.
//   off(row, col) = (col>>3)*256 + row*8 + (col&7)   [halfs; 32-row tiles]
// A-read offset linear in ks (ks*512 halfs = 1024 B) -> one base VGPR +
// immediate offsets (max 15*1024 B, fits 16-bit ds imm).
// LDS: act A (16 KiB) + act B (16 KiB) + x (4 KiB) = 36864 B -> 4 blocks/CU.
// Ping-pong (read A, write B) removes the in-layer barrier: ONE barrier per
// layer (9 vs R16's 18 per block) and waves decouple within a layer — a
// fast wave runs ahead into its epilogue + next layer's cold W loads while
// slow waves finish their k-loop.
// ---------------------------------------------------------------------------
__device__ __forceinline__ int cmaj32(int row, int col) {
    return ((col >> 3) << 8) + (row << 3) + (col & 7);
}

// ---------------------------------------------------------------------------
// Weight pre-pack (unchanged, proven R5-R16): fp32 (K,N) row-major -> fp16
// fragment order; lane L holds W[kt*16 + 8*(L>>5) + j][nt*32 + (L&31)].
// Fed to the MFMA *A* operand so D = C^T. K zero-padded: L1 39->64 (KT=4),
// L5 295->320 (KT=20), others 256 (KT=16). L9 N 4->32. Tile starts (1KB):
// {0,32,160,288,416,576,704,832,960}, total 976 tiles = 999424 B in d_ws.
// ---------------------------------------------------------------------------
__global__ void pack_w32(const float* __restrict__ w1, const float* __restrict__ w2,
                         const float* __restrict__ w3, const float* __restrict__ w4,
                         const float* __restrict__ w5, const float* __restrict__ w6,
                         const float* __restrict__ w7, const float* __restrict__ w8,
                         const float* __restrict__ w9, _Float16* __restrict__ dst) {
    const int tileStart[10] = {0, 32, 160, 288, 416, 576, 704, 832, 960, 976};
    const int Ks[9] = {39, 256, 256, 256, 295, 256, 256, 256, 256};
    const int Ns[9] = {256, 256, 256, 256, 256, 256, 256, 256, 4};
    const int Tn[9] = {8, 8, 8, 8, 8, 8, 8, 8, 1};
    const float* ws[9] = {w1, w2, w3, w4, w5, w6, w7, w8, w9};

    int g = blockIdx.x * blockDim.x + threadIdx.x;
    int tile = g >> 6, lane = g & 63;
    if (tile >= 976) return;
    int layer = 0;
    while (tile >= tileStart[layer + 1]) layer++;
    int t = tile - tileStart[layer];
    int tn = Tn[layer];
    int kt = t / tn, nt = t - kt * tn;
    int k0 = kt * 16 + (lane >> 5) * 8;
    int n = nt * 32 + (lane & 31);
    const float* w = ws[layer];
    int K = Ks[layer], N = Ns[layer];
    _Float16 v[8];
#pragma unroll
    for (int j = 0; j < 8; j++) {
        int k = k0 + j;
        v[j] = (k < K && n < N) ? (_Float16)w[k * N + n] : (_Float16)0.f;
    }
    *(half8*)(dst + (size_t)tile * 512 + lane * 8) = *(half8*)v;
}

// A-fragment load: base encodes (lhi, row); offset linear in ks.
// AMODE 0: act. 1: ks>=KS0 from x (layer-5 skip). 2: entirely x (layer 1).
template <int AMODE, int KS0>
__device__ __forceinline__ half8 ldA(const _Float16* aB, const _Float16* xB, int ks) {
    if (AMODE == 2) return *(const half8*)(xB + ks * 512);
    if (AMODE == 1 && ks >= KS0) return *(const half8*)(xB + (ks - KS0) * 512);
    return *(const half8*)(aB + ks * 512);
}

// ---------------------------------------------------------------------------
// One fused layer: C(32x256) = relu(A(32xK) @ W + b), ping-pong LDS->LDS,
// NO internal barrier. Wave tile = 1m x 2n (32 rows x 64 cols): acc 32 AGPR;
// unroll x2 depth-2 W ring; bias folded into acc init; b64 epilogue.
// Live regs ~92 (32 acc + ~60 arch) << (256,4)'s 128 cap — no spill risk.
// ---------------------------------------------------------------------------
template <int KT, int AMODE, int KS0>
__device__ __forceinline__ void layerT(const _Float16* abuf,
                                       const _Float16* __restrict__ xbuf,
                                       const half8* __restrict__ wq,
                                       const float* __restrict__ bias,
                                       _Float16* obuf,
                                       int lane, int wave) {
    static_assert((KT & 3) == 0 && KT >= 4, "KT must be a multiple of 4");
    const int l31 = lane & 31, lhi = lane >> 5;
    const _Float16* aB = abuf + lhi * 256 + l31 * 8;
    const _Float16* xB = xbuf + lhi * 256 + l31 * 8;
    // W frag (kstep ks, n-tile wave*2+n): wl[ks*512 + n*64]
    const half8* wl = wq + (wave * 2) * 64 + lane;
    // Bias -> acc init: acc{0,1} element g*4+r is channel
    // wave*64 + {0,32} + lhi*4 + g*8 + r.
    floatx16 acc0, acc1;
#pragma unroll
    for (int g = 0; g < 4; g++) {
        floatx4 b0 = *(const floatx4*)(bias + wave * 64 + lhi * 4 + g * 8);
        floatx4 b1 = *(const floatx4*)(bias + wave * 64 + 32 + lhi * 4 + g * 8);
#pragma unroll
        for (int r = 0; r < 4; r++) { acc0[g * 4 + r] = b0[r]; acc1[g * 4 + r] = b1[r]; }
    }
    half8 w0a = wl[0], w0b = wl[64];
    half8 w1a = wl[512], w1b = wl[512 + 64];
#pragma unroll 1
    for (int ks = 0; ks < KT - 4; ks += 4) {
        half8 w2a = wl[(ks + 2) * 512], w2b = wl[(ks + 2) * 512 + 64];
        half8 w3a = wl[(ks + 3) * 512], w3b = wl[(ks + 3) * 512 + 64];
        half8 a = ldA<AMODE, KS0>(aB, xB, ks);
        acc0 = __builtin_amdgcn_mfma_f32_32x32x16_f16(w0a, a, acc0, 0, 0, 0);
        acc1 = __builtin_amdgcn_mfma_f32_32x32x16_f16(w0b, a, acc1, 0, 0, 0);
        a = ldA<AMODE, KS0>(aB, xB, ks + 1);
        acc0 = __builtin_amdgcn_mfma_f32_32x32x16_f16(w1a, a, acc0, 0, 0, 0);
        acc1 = __builtin_amdgcn_mfma_f32_32x32x16_f16(w1b, a, acc1, 0, 0, 0);
        w0a = wl[(ks + 4) * 512]; w0b = wl[(ks + 4) * 512 + 64];
        w1a = wl[(ks + 5) * 512]; w1b = wl[(ks + 5) * 512 + 64];
        a = ldA<AMODE, KS0>(aB, xB, ks + 2);
        acc0 = __builtin_amdgcn_mfma_f32_32x32x16_f16(w2a, a, acc0, 0, 0, 0);
        acc1 = __builtin_amdgcn_mfma_f32_32x32x16_f16(w2b, a, acc1, 0, 0, 0);
        a = ldA<AMODE, KS0>(aB, xB, ks + 3);
        acc0 = __builtin_amdgcn_mfma_f32_32x32x16_f16(w3a, a, acc0, 0, 0, 0);
        acc1 = __builtin_amdgcn_mfma_f32_32x32x16_f16(w3b, a, acc1, 0, 0, 0);
    }
    {   // tail: last 4 k-steps (w0/w1 hold KT-4, KT-3)
        half8 w2a = wl[(KT - 2) * 512], w2b = wl[(KT - 2) * 512 + 64];
        half8 w3a = wl[(KT - 1) * 512], w3b = wl[(KT - 1) * 512 + 64];
        half8 a = ldA<AMODE, KS0>(aB, xB, KT - 4);
        acc0 = __builtin_amdgcn_mfma_f32_32x32x16_f16(w0a, a, acc0, 0, 0, 0);
        acc1 = __builtin_amdgcn_mfma_f32_32x32x16_f16(w0b, a, acc1, 0, 0, 0);
        a = ldA<AMODE, KS0>(aB, xB, KT - 3);
        acc0 = __builtin_amdgcn_mfma_f32_32x32x16_f16(w1a, a, acc0, 0, 0, 0);
        acc1 = __builtin_amdgcn_mfma_f32_32x32x16_f16(w1b, a, acc1, 0, 0, 0);
        a = ldA<AMODE, KS0>(aB, xB, KT - 2);
        acc0 = __builtin_amdgcn_mfma_f32_32x32x16_f16(w2a, a, acc0, 0, 0, 0);
        acc1 = __builtin_amdgcn_mfma_f32_32x32x16_f16(w2b, a, acc1, 0, 0, 0);
        a = ldA<AMODE, KS0>(aB, xB, KT - 1);
        acc0 = __builtin_amdgcn_mfma_f32_32x32x16_f16(w3a, a, acc0, 0, 0, 0);
        acc1 = __builtin_amdgcn_mfma_f32_32x32x16_f16(w3b, a, acc1, 0, 0, 0);
    }
    // Epilogue (no barrier — output buffer is the other ping-pong buffer):
    // relu + fp16 cvt + b64 writes. D=C^T: row m = l31, col n =
    // wave*64 + ni*32 + lhi*4 + g*8 + r -> chunk = wave*8 + ni*4 + g,
    // inner = lhi*4 + r. One base + immediate offsets.
    _Float16* ob = obuf + wave * 2048 + l31 * 8 + lhi * 4;
#pragma unroll
    for (int ni = 0; ni < 2; ni++) {
        const floatx16& accv = ni ? acc1 : acc0;
#pragma unroll
        for (int g = 0; g < 4; g++) {
            half4v h;
#pragma unroll
            for (int r = 0; r < 4; r++) {
                float v = accv[g * 4 + r];
                v = v > 0.f ? v : 0.f;
                h[r] = (_Float16)v;
            }
            *(half4v*)(ob + (ni * 4 + g) * 256) = h;
        }
    }
}

// Layer 9 (swapped): 256 -> 4 (N padded to 32). Wave 0 handles the 32-row
// m-tile; D[n][m]: lanes 0..31 hold n=r (r<4) for row m=l31.
__device__ __forceinline__ void layer9T(const _Float16* abuf,
                                        const half8* __restrict__ wq,
                                        const float* __restrict__ b9,
                                        float* __restrict__ out, long r0,
                                        int lane, int wave) {
    if (wave != 0) return;
    const int l31 = lane & 31, lhi = lane >> 5;
    const _Float16* aB = abuf + lhi * 256 + l31 * 8;
    floatx16 acc = {};
    const half8* wl = wq + lane;
    half8 wc = wl[0];
#pragma unroll 1
    for (int ks = 0; ks < 15; ks++) {
        half8 wn = wl[(ks + 1) * 64];
        half8 a = *(const half8*)(aB + ks * 512);
        acc = __builtin_amdgcn_mfma_f32_32x32x16_f16(wc, a, acc, 0, 0, 0);
        wc = wn;
    }
    {
        half8 a = *(const half8*)(aB + 15 * 512);
        acc = __builtin_amdgcn_mfma_f32_32x32x16_f16(wc, a, acc, 0, 0, 0);
    }
    if (lhi == 0) {
        asm volatile("" ::: "memory");
        floatx4 b4 = *(const floatx4*)(b9);
        floatx4 o;
#pragma unroll
        for (int r = 0; r < 4; r++) o[r] = acc[r] + b4[r];
        *(floatx4*)(out + (r0 + l31) * 4) = o;
    }
}

__global__ __launch_bounds__(256, 4) void mlp_fused(
    const float* __restrict__ x, const _Float16* __restrict__ wpk,
    const float* __restrict__ b1, const float* __restrict__ b2,
    const float* __restrict__ b3, const float* __restrict__ b4,
    const float* __restrict__ b5, const float* __restrict__ b6,
    const float* __restrict__ b7, const float* __restrict__ b8,
    const float* __restrict__ b9, float* __restrict__ out) {
    // 2 x 16 KiB act ping-pong + 4 KiB x tile = 36864 B; 4-wave blocks;
    // 4 blocks/CU (LDS-capped) = 16 waves/CU = 4 waves/SIMD; regs ~92/wave.
    __shared__ _Float16 lds[2 * 32 * 256 + 32 * 64];
    _Float16* bufA = lds;
    _Float16* bufB = lds + 32 * 256;
    _Float16* xbuf = lds + 2 * 32 * 256;
    const int tid = threadIdx.x;
    const int lane = tid & 63, wave = tid >> 6;
    const long r0 = (long)blockIdx.x * 32;

    // Stage x (chunk-major): zero pad cols (39..63), fill cols 0..38.
    for (int i = tid; i < 32 * 25; i += 256) {
        int row = i / 25, col = 39 + (i - row * 25);
        xbuf[cmaj32(row, col)] = (_Float16)0.f;
    }
    for (int i = tid; i < 32 * 39; i += 256) {
        int row = i / 39, col = i - row * 39;
        xbuf[cmaj32(row, col)] = (_Float16)x[r0 * 39 + i];  // contiguous 1248 floats
    }
    __syncthreads();

    const half8* wp = (const half8*)wpk;  // tile = 64 half8 (1 KB)
    const half8* w1q = wp + (size_t)0 * 64;
    const half8* w2q = wp + (size_t)32 * 64;
    const half8* w3q = wp + (size_t)160 * 64;
    const half8* w4q = wp + (size_t)288 * 64;
    const half8* w5q = wp + (size_t)416 * 64;
    const half8* w6q = wp + (size_t)576 * 64;
    const half8* w7q = wp + (size_t)704 * 64;
    const half8* w8q = wp + (size_t)832 * 64;
    const half8* w9q = wp + (size_t)960 * 64;

    // Ping-pong chain, ONE barrier per layer.
    layerT<4, 2, 0>(xbuf, xbuf, w1q, b1, bufA, lane, wave);   // x -> A
    __syncthreads();
    layerT<16, 0, 0>(bufA, xbuf, w2q, b2, bufB, lane, wave);  // A -> B
    __syncthreads();
    layerT<16, 0, 0>(bufB, xbuf, w3q, b3, bufA, lane, wave);  // B -> A
    __syncthreads();
    layerT<16, 0, 0>(bufA, xbuf, w4q, b4, bufB, lane, wave);  // A -> B
    __syncthreads();
    layerT<20, 1, 16>(bufB, xbuf, w5q, b5, bufA, lane, wave); // B(+x) -> A
    __syncthreads();
    layerT<16, 0, 0>(bufA, xbuf, w6q, b6, bufB, lane, wave);  // A -> B
    __syncthreads();
    layerT<16, 0, 0>(bufB, xbuf, w7q, b7, bufA, lane, wave);  // B -> A
    __syncthreads();
    layerT<16, 0, 0>(bufA, xbuf, w8q, b8, bufB, lane, wave);  // A -> B
    __syncthreads();
    layer9T(bufB, w9q, b9, out, r0, lane, wave);              // B -> out
}

extern "C" void kernel_launch(void* const* d_in, const int* in_sizes, int n_in,
                              void* d_out, int out_size, void* d_ws, size_t ws_size,
                              hipStream_t stream) {
    const float* x = (const float*)d_in[0];
    const float* w[9];
    const float* b[9];
    for (int i = 0; i < 9; i++) {
        w[i] = (const float*)d_in[1 + 2 * i];
        b[i] = (const float*)d_in[2 + 2 * i];
    }
    _Float16* wpk = (_Float16*)d_ws;  // 999424 B

    pack_w32<<<244, 256, 0, stream>>>(w[0], w[1], w[2], w[3], w[4], w[5], w[6], w[7], w[8], wpk);
    mlp_fused<<<262144 / 32, 256, 0, stream>>>(x, wpk, b[0], b[1], b[2], b[3], b[4],
                                               b[5], b[6], b[7], b[8], (float*)d_out);
}